// Round 20
// baseline (132.048 us; speedup 1.0000x reference)
//
#include <hip/hip_runtime.h>

#define HW 512
#define NSTATE (HW * HW)   // 262144
#define NC4_X 196608       // x as float4 (3*H*W/4)
#define NC4_POLROW 262144  // Wpol row stride in float4 (4 MiB)
#define NC4_V 65536        // v as float4

#define CH4 1024   // float4 per wave-chunk (16 KB)
#define NCH_X 192  // chunks per W1 row

// ws layout (float offsets)
#define WS_PART1 0      // 192*32 = 6144
#define WS_PARTP 6144   // 256*32 = 8192
#define WS_P 14400      // 262144
#define WS_RD (WS_P + NSTATE)
#define WS_V (WS_RD + NSTATE)

#define SGB __builtin_amdgcn_sched_group_barrier

__device__ __forceinline__ float wred(float a) {
  a += __shfl_xor(a, 32);
  a += __shfl_xor(a, 16);
  a += __shfl_xor(a, 8);
  a += __shfl_xor(a, 4);
  a += __shfl_xor(a, 2);
  a += __shfl_xor(a, 1);
  return a;
}

__device__ __forceinline__ float span_dot(const float4* __restrict__ wp,
                                          const float4* __restrict__ xp) {
  float acc = 0.f;
#pragma unroll
  for (int bt = 0; bt < 2; ++bt) {
    float4 w[8], xv[8];
#pragma unroll
    for (int j = 0; j < 8; ++j) w[j] = wp[bt * 512 + j * 64];
#pragma unroll
    for (int j = 0; j < 8; ++j) xv[j] = xp[bt * 512 + j * 64];
    SGB(0x020, 16, 0);
#pragma unroll
    for (int j = 0; j < 8; ++j)
      acc += w[j].x * xv[j].x + w[j].y * xv[j].y + w[j].z * xv[j].z +
             w[j].w * xv[j].w;
  }
  return acc;
}

// ---------------------------------------------------------------------------
// K1: W1@x partials, flat-linear span_dot (fast shape). 1536 blocks.
// ---------------------------------------------------------------------------
__global__ __launch_bounds__(256) void mv_w1(const float4* __restrict__ W1,
                                             const float4* __restrict__ x,
                                             float* __restrict__ part1) {
  int b = blockIdx.x;
  int row = b / 48, cb = b - row * 48;
  int tid = threadIdx.x, wave = tid >> 6, lane = tid & 63;
  int ch = cb * 4 + wave;
  const float4* __restrict__ wp =
      W1 + (size_t)row * NC4_X + (size_t)ch * CH4 + lane;
  const float4* __restrict__ xp = x + (size_t)ch * CH4 + lane;
  float acc = span_dot(wp, xp);
  acc = wred(acc);
  if (lane == 0) part1[ch * 32 + row] = acc;
}

// ---------------------------------------------------------------------------
// K2: rop_h REWRITE (R20). R19 measured the old body at 77 µs / 1.33 TB/s /
// VGPR=32: the 32 shfl_xor per 8-load batch force the allocator to collapse
// the load cluster (19-round lesson: mid-loop cross-lane ops = 2.5 TB/s;
// lane-local span_dot shape = 7+ TB/s). New body: ONE THREAD = ONE OUTPUT
// ROW. Row o = 16 consecutive float4 at W + o*16 — a single-base 16-load
// cluster (SGB-pinned), dotted against h2 via 16 broadcast LDS reads. Zero
// shuffles, zero dots-bounce, coalesced stores. finish_h prologue kept.
// ---------------------------------------------------------------------------
__global__ __launch_bounds__(256) void rop_h(
    const float* __restrict__ part1, const float* __restrict__ b1,
    const float* __restrict__ W2, const float* __restrict__ b2,
    const float4* __restrict__ Wro4, const float* __restrict__ bro,
    const float4* __restrict__ Wri4, const float* __restrict__ bri,
    const float4* __restrict__ Wp4, const float* __restrict__ bp,
    float* __restrict__ p_out, float* __restrict__ rd_out) {
  __shared__ float red[8][32];
  __shared__ float h1s[32];
  __shared__ float h2s[64];
  int tid = threadIdx.x;
  // --- finish_h prologue (block-local, redundant across blocks) ---
  {
    int r = tid & 31, g = tid >> 5;
    float s = 0.f;
    for (int b = g; b < NCH_X; b += 8) s += part1[b * 32 + r];
    red[g][r] = s;
  }
  __syncthreads();
  if (tid < 32) {
    float t = b1[tid];
    for (int g = 0; g < 8; ++g) t += red[g][tid];
    h1s[tid] = fmaxf(t, 0.f);
  }
  __syncthreads();
  if (tid < 64) {
    float t = b2[tid];
    for (int k = 0; k < 32; ++k) t += W2[tid * 32 + k] * h1s[k];
    h2s[tid] = fmaxf(t, 0.f);
  }
  __syncthreads();
  // --- lane-local rop body ---
  int o = blockIdx.x * 256 + tid;
  const float4* __restrict__ h4p = (const float4*)h2s;
  const float4* mats[3] = {Wro4, Wri4, Wp4};
  float d[3];
#pragma unroll
  for (int m = 0; m < 3; ++m) {
    const float4* __restrict__ W = mats[m] + (size_t)o * 16;
    float4 w[16];
#pragma unroll
    for (int j = 0; j < 16; ++j) w[j] = W[j];
    SGB(0x020, 16, 0);  // keep the 16-load cluster intact
    float acc = 0.f;
#pragma unroll
    for (int j = 0; j < 16; ++j) {
      float4 h = h4p[j];  // broadcast LDS read (all lanes same addr)
      acc += w[j].x * h.x + w[j].y * h.y + w[j].z * h.z + w[j].w * h.w;
    }
    d[m] = acc;
  }
  float dro = d[0] + bro[o];
  float dri = d[1] + bri[o];
  float dp = d[2] + bp[o];
  float sro = 1.f / (1.f + __expf(-dro));
  float sri = 1.f / (1.f + __expf(-dri));
  float pv = 1.f / (1.f + __expf(-dp));
  p_out[o] = pv;
  rd_out[o] = sri - sro;
}

// ---------------------------------------------------------------------------
// K3: valiter (R17 rewrite, measured ~9 µs). 1024 blocks x 384 threads.
// ---------------------------------------------------------------------------
#define VTILE 16
#define VHALO 10
#define ULW 44
#define ULH 38
__device__ __forceinline__ void row_win(const float* __restrict__ r,
                                        float e[6]) {
  float4 L = *reinterpret_cast<const float4*>(r - 4);
  float4 M = *reinterpret_cast<const float4*>(r);
  float4 R = *reinterpret_cast<const float4*>(r + 4);
  e[0] = L.w; e[1] = M.x; e[2] = M.y; e[3] = M.z; e[4] = M.w; e[5] = R.x;
}
__global__ __launch_bounds__(384) void valiter_kernel(
    const float* __restrict__ p, const float* __restrict__ rd,
    float* __restrict__ vout) {
  __shared__ float ua[ULH * ULW];
  __shared__ float ub[ULH * ULW];
  int tid = threadIdx.x;
  int blk = blockIdx.x;
  int ti = blk >> 5, tj = blk & 31;
  for (int idx = tid; idx < ULH * ULW; idx += 384) {
    ua[idx] = 0.f;
    ub[idx] = 0.f;
  }
  int i = tid / 9, j4 = tid - i * 9;
  bool active = (i < 36);
  int cb = 4 + 4 * j4;
  float pp[4], rr[4];
  if (active) {
    int gi = ti * VTILE - VHALO + i;
    int gj0 = tj * VTILE - VHALO + 4 * j4;
#pragma unroll
    for (int k = 0; k < 4; ++k) {
      int gj = gj0 + k;
      bool ok = (gi >= 0) & (gi < HW) & (gj >= 0) & (gj < HW);
      int gidx = gi * HW + gj;
      pp[k] = ok ? p[gidx] : 0.f;
      rr[k] = ok ? rd[gidx] : 0.f;
    }
  }
  __syncthreads();
  if (active) {
    *reinterpret_cast<float4*>(&ua[(i + 1) * ULW + cb]) =
        make_float4(rr[0], rr[1], rr[2], rr[3]);
  }
  __syncthreads();
  float* src = ua;
  float* dst = ub;
  for (int q = 0; q < 9; ++q) {
    int lo = q + 1, hi = 35 - q;
    if (active && i >= lo && i < hi && (4 * j4 + 4) > lo && (4 * j4) < hi) {
      float eA[6], eB[6], eC[6];
      row_win(src + i * ULW + cb, eA);
      row_win(src + (i + 1) * ULW + cb, eB);
      row_win(src + (i + 2) * ULW + cb, eC);
      float res[4];
#pragma unroll
      for (int k = 0; k < 4; ++k) {
        float a = fmaxf(fmaxf(eA[k], eA[k + 1]), eA[k + 2]);
        float c = fmaxf(fmaxf(eC[k], eC[k + 1]), eC[k + 2]);
        float b = fmaxf(eB[k], eB[k + 2]);
        float m = fmaxf(fmaxf(a, c), b);
        res[k] = m * pp[k] + rr[k];
      }
      *reinterpret_cast<float4*>(&dst[(i + 1) * ULW + cb]) =
          make_float4(res[0], res[1], res[2], res[3]);
    }
    __syncthreads();
    float* t_ = src;
    src = dst;
    dst = t_;
  }
  if (active && i >= 10 && i < 26 && (4 * j4 + 4) > 10 && (4 * j4) < 26) {
    float eA[6], eB[6], eC[6];
    row_win(src + i * ULW + cb, eA);
    row_win(src + (i + 1) * ULW + cb, eB);
    row_win(src + (i + 2) * ULW + cb, eC);
#pragma unroll
    for (int k = 0; k < 4; ++k) {
      int cj = 4 * j4 + k;
      if (cj >= 10 && cj < 26) {
        float a = fmaxf(fmaxf(eA[k], eA[k + 1]), eA[k + 2]);
        float c = fmaxf(fmaxf(eC[k], eC[k + 1]), eC[k + 2]);
        float b = fmaxf(eB[k], eB[k + 2]);
        float m = fmaxf(fmaxf(a, c), b);
        vout[(ti * VTILE + i - 10) * HW + tj * VTILE + cj - 10] = m;
      }
    }
  }
}

// ---------------------------------------------------------------------------
// K4: all Wpol in one flat span_dot sweep (measured warm 17.1 µs / 7.5 TB/s).
// ---------------------------------------------------------------------------
__global__ __launch_bounds__(256) void mv_pol(const float4* __restrict__ Wpol,
                                              const float4* __restrict__ x,
                                              const float4* __restrict__ v,
                                              float* __restrict__ partP) {
  int b = blockIdx.x;
  int tid = threadIdx.x, wave = tid >> 6, lane = tid & 63;
  int f = b * 4 + wave;
  int row = f >> 8, rc = f & 255;
  const float4* __restrict__ wp = Wpol + (size_t)f * CH4 + lane;
  const float4* __restrict__ xp =
      (rc < 64) ? (v + (size_t)rc * CH4 + lane)
                : (x + (size_t)(rc - 64) * CH4 + lane);
  float acc = span_dot(wp, xp);
  acc = wred(acc);
  if (lane == 0) partP[rc * 32 + row] = acc;
}

// ---------------------------------------------------------------------------
// K5: finish_pol (1 block).
// ---------------------------------------------------------------------------
__global__ __launch_bounds__(1024) void finish_pol(
    const float* __restrict__ partP, const float* __restrict__ bpol,
    const float* __restrict__ Whead, const float* __restrict__ bhead,
    const float* __restrict__ v, const int* __restrict__ pos,
    float* __restrict__ out) {
  __shared__ float red[32][32];
  __shared__ float hp[32];
  __shared__ float logits[8];
  int tid = threadIdx.x;
  int row = tid & 31, grp = tid >> 5;
  float s = 0.f;
  for (int b = grp; b < 256; b += 32) s += partP[b * 32 + row];
  red[grp][row] = s;
  __syncthreads();
  if (tid < 32) {
    float t = bpol[tid];
    for (int g = 0; g < 32; ++g) t += red[g][tid];
    hp[tid] = fmaxf(t, 0.f);
  }
  __syncthreads();
  if (tid < 8) {
    float t = bhead[tid];
    for (int k = 0; k < 32; ++k) t += Whead[tid * 32 + k] * hp[k];
    logits[tid] = t;
  }
  __syncthreads();
  if (tid == 0) {
    float mx = logits[0];
    for (int j = 1; j < 8; ++j) mx = fmaxf(mx, logits[j]);
    float e[8], sum = 0.f;
    for (int j = 0; j < 8; ++j) {
      e[j] = __expf(logits[j] - mx);
      sum += e[j];
    }
    for (int j = 0; j < 8; ++j) out[j] = e[j] / sum;
    out[8] = v[pos[0] * HW + pos[1]];
  }
}

extern "C" void kernel_launch(void* const* d_in, const int* in_sizes, int n_in,
                              void* d_out, int out_size, void* d_ws,
                              size_t ws_size, hipStream_t stream) {
  const float* x = (const float*)d_in[0];
  const int* pos = (const int*)d_in[1];
  const float* W1 = (const float*)d_in[2];
  const float* b1 = (const float*)d_in[3];
  const float* W2 = (const float*)d_in[4];
  const float* b2 = (const float*)d_in[5];
  const float* Wro = (const float*)d_in[6];
  const float* bro = (const float*)d_in[7];
  const float* Wri = (const float*)d_in[8];
  const float* bri = (const float*)d_in[9];
  const float* Wp = (const float*)d_in[10];
  const float* bp = (const float*)d_in[11];
  const float* Wpol = (const float*)d_in[12];
  const float* bpol = (const float*)d_in[13];
  const float* Whead = (const float*)d_in[14];
  const float* bhead = (const float*)d_in[15];
  float* ws = (float*)d_ws;
  float* out = (float*)d_out;

  float* part1 = ws + WS_PART1;
  float* partP = ws + WS_PARTP;
  float* pbuf = ws + WS_P;
  float* rdbuf = ws + WS_RD;
  float* vbuf = ws + WS_V;

  // K1: W1@x partials
  mv_w1<<<1536, 256, 0, stream>>>((const float4*)W1, (const float4*)x, part1);
  // K2: h1->h2 (per-block prologue) + lane-local rop
  rop_h<<<1024, 256, 0, stream>>>(part1, b1, W2, b2, (const float4*)Wro, bro,
                                  (const float4*)Wri, bri, (const float4*)Wp,
                                  bp, pbuf, rdbuf);
  // K3: 10 value-iteration steps
  valiter_kernel<<<1024, 384, 0, stream>>>(pbuf, rdbuf, vbuf);
  // K4: all Wpol partials
  mv_pol<<<2048, 256, 0, stream>>>((const float4*)Wpol, (const float4*)x,
                                   (const float4*)vbuf, partP);
  // K5: heads + softmax + state value
  finish_pol<<<1, 1024, 0, stream>>>(partP, bpol, Whead, bhead, vbuf, pos,
                                     out);
}

// Round 21
// 115.277 us; speedup vs baseline: 1.1455x; 1.1455x over previous
//
#include <hip/hip_runtime.h>

#define HW 512
#define NSTATE (HW * HW)   // 262144
#define NC4_X 196608       // x as float4 (3*H*W/4)
#define NC4_POLROW 262144  // Wpol row stride in float4 (4 MiB)
#define NC4_V 65536        // v as float4

#define CH4 1024   // float4 per wave-chunk (16 KB)
#define NCH_X 192  // chunks per W1 row

// ws layout (float offsets)
#define WS_PART1 0       // 6144
#define WS_PARTP 6144    // 8192
#define WS_H2 14336      // 64
#define WS_DRO 16384     // 262144
#define WS_DRI 278528    // 262144
#define WS_DP 540672     // 262144
#define WS_V 802816      // 262144

#define SGB __builtin_amdgcn_sched_group_barrier

__device__ __forceinline__ float wred(float a) {
  a += __shfl_xor(a, 32);
  a += __shfl_xor(a, 16);
  a += __shfl_xor(a, 8);
  a += __shfl_xor(a, 4);
  a += __shfl_xor(a, 2);
  a += __shfl_xor(a, 1);
  return a;
}

__device__ __forceinline__ float span_dot(const float4* __restrict__ wp,
                                          const float4* __restrict__ xp) {
  float acc = 0.f;
#pragma unroll
  for (int bt = 0; bt < 2; ++bt) {
    float4 w[8], xv[8];
#pragma unroll
    for (int j = 0; j < 8; ++j) w[j] = wp[bt * 512 + j * 64];
#pragma unroll
    for (int j = 0; j < 8; ++j) xv[j] = xp[bt * 512 + j * 64];
    SGB(0x020, 16, 0);
#pragma unroll
    for (int j = 0; j < 8; ++j)
      acc += w[j].x * xv[j].x + w[j].y * xv[j].y + w[j].z * xv[j].z +
             w[j].w * xv[j].w;
  }
  return acc;
}

// ---------------------------------------------------------------------------
// K1: W1@x partials, flat-linear span_dot. 1536 blocks. (~12 µs in-situ)
// ---------------------------------------------------------------------------
__global__ __launch_bounds__(256) void mv_w1(const float4* __restrict__ W1,
                                             const float4* __restrict__ x,
                                             float* __restrict__ part1) {
  int b = blockIdx.x;
  int row = b / 48, cb = b - row * 48;
  int tid = threadIdx.x, wave = tid >> 6, lane = tid & 63;
  int ch = cb * 4 + wave;
  const float4* __restrict__ wp =
      W1 + (size_t)row * NC4_X + (size_t)ch * CH4 + lane;
  const float4* __restrict__ xp = x + (size_t)ch * CH4 + lane;
  float acc = span_dot(wp, xp);
  acc = wred(acc);
  if (lane == 0) part1[ch * 32 + row] = acc;
}

// ---------------------------------------------------------------------------
// K2: finish_h (1 block, measured cheap in R17 form).
// ---------------------------------------------------------------------------
__global__ __launch_bounds__(1024) void finish_h(
    const float* __restrict__ partials, const float* __restrict__ b1,
    const float* __restrict__ W2, const float* __restrict__ b2,
    float* __restrict__ h2out) {
  __shared__ float red[32][32];
  __shared__ float h1[32];
  int tid = threadIdx.x;
  int row = tid & 31, grp = tid >> 5;
  float s = 0.f;
  for (int b = grp; b < NCH_X; b += 32) s += partials[b * 32 + row];
  red[grp][row] = s;
  __syncthreads();
  if (tid < 32) {
    float t = b1[tid];
    for (int g = 0; g < 32; ++g) t += red[g][tid];
    h1[tid] = fmaxf(t, 0.f);
  }
  __syncthreads();
  if (tid < 64) {
    float t = b2[tid];
    for (int k = 0; k < 32; ++k) t += W2[tid * 32 + k] * h1[k];
    h2out[tid] = fmaxf(t, 0.f);
  }
}

// ---------------------------------------------------------------------------
// K3: rop_part (R21). mv_pol's exact skeleton: 3072 homogeneous blocks,
// block (m = b>>10, c = b&1023); each wave sweeps ONE 16 KB span of ONE
// matrix (16 loads up front), 16-lane-group dots, LDS bounce, coalesced
// store of RAW dots. Bias/sigmoid/combine deferred to valiter's load stage.
// R5's slow form differed ONLY in: 48 KB per wave across 3 interleaved
// streams + sigmoid tail — this isolates that variable.
// ---------------------------------------------------------------------------
__global__ __launch_bounds__(256) void rop_part(
    const float4* __restrict__ Wro4, const float4* __restrict__ Wri4,
    const float4* __restrict__ Wp4, const float* __restrict__ h2,
    float* __restrict__ dro, float* __restrict__ dri,
    float* __restrict__ dp) {
  __shared__ float dots[4][64];
  int b = blockIdx.x;  // [0,3072)
  int m = b >> 10;     // matrix 0..2
  int c = b & 1023;    // 64KB chunk
  int tid = threadIdx.x, wave = tid >> 6, lane = tid & 63;
  int k = lane & 15, grp = lane >> 4;
  const float4* __restrict__ W = (m == 0) ? Wro4 : ((m == 1) ? Wri4 : Wp4);
  float* __restrict__ D = (m == 0) ? dro : ((m == 1) ? dri : dp);
  float4 h4 = ((const float4*)h2)[k];
  const float4* __restrict__ wp = W + ((size_t)c * 4 + wave) * 1024 + lane;
  float part[16];
#pragma unroll
  for (int bt = 0; bt < 2; ++bt) {
    float4 w[8];
#pragma unroll
    for (int j = 0; j < 8; ++j) w[j] = wp[(bt * 8 + j) * 64];
    SGB(0x020, 8, 0);
#pragma unroll
    for (int j = 0; j < 8; ++j)
      part[bt * 8 + j] =
          w[j].x * h4.x + w[j].y * h4.y + w[j].z * h4.z + w[j].w * h4.w;
  }
#pragma unroll
  for (int j = 0; j < 16; ++j) {
    part[j] += __shfl_xor(part[j], 8);
    part[j] += __shfl_xor(part[j], 4);
    part[j] += __shfl_xor(part[j], 2);
    part[j] += __shfl_xor(part[j], 1);
  }
  if (k == 0) {
#pragma unroll
    for (int j = 0; j < 16; ++j) dots[wave][j * 4 + grp] = part[j];
  }
  __syncthreads();
  D[(size_t)c * 256 + tid] = dots[tid >> 6][tid & 63];
}

// ---------------------------------------------------------------------------
// K4: valiter (R17 structure) + sigmoid/bias/combine absorbed in the load
// stage: p = sig(dp+bp), rd = sig(dri+bri) - sig(dro+bro) per ok-cell.
// ---------------------------------------------------------------------------
#define VTILE 16
#define VHALO 10
#define ULW 44
#define ULH 38
__device__ __forceinline__ void row_win(const float* __restrict__ r,
                                        float e[6]) {
  float4 L = *reinterpret_cast<const float4*>(r - 4);
  float4 M = *reinterpret_cast<const float4*>(r);
  float4 R = *reinterpret_cast<const float4*>(r + 4);
  e[0] = L.w; e[1] = M.x; e[2] = M.y; e[3] = M.z; e[4] = M.w; e[5] = R.x;
}
__global__ __launch_bounds__(384) void valiter_kernel(
    const float* __restrict__ dro, const float* __restrict__ dri,
    const float* __restrict__ dp, const float* __restrict__ bro,
    const float* __restrict__ bri, const float* __restrict__ bp,
    float* __restrict__ vout) {
  __shared__ float ua[ULH * ULW];
  __shared__ float ub[ULH * ULW];
  int tid = threadIdx.x;
  int blk = blockIdx.x;
  int ti = blk >> 5, tj = blk & 31;
  for (int idx = tid; idx < ULH * ULW; idx += 384) {
    ua[idx] = 0.f;
    ub[idx] = 0.f;
  }
  int i = tid / 9, j4 = tid - i * 9;
  bool active = (i < 36);
  int cb = 4 + 4 * j4;
  float pp[4], rr[4];
  if (active) {
    int gi = ti * VTILE - VHALO + i;
    int gj0 = tj * VTILE - VHALO + 4 * j4;
#pragma unroll
    for (int k = 0; k < 4; ++k) {
      int gj = gj0 + k;
      bool ok = (gi >= 0) & (gi < HW) & (gj >= 0) & (gj < HW);
      if (ok) {
        int g = gi * HW + gj;
        float sro = 1.f / (1.f + __expf(-(dro[g] + bro[g])));
        float sri = 1.f / (1.f + __expf(-(dri[g] + bri[g])));
        pp[k] = 1.f / (1.f + __expf(-(dp[g] + bp[g])));
        rr[k] = sri - sro;
      } else {
        pp[k] = 0.f;
        rr[k] = 0.f;
      }
    }
  }
  __syncthreads();
  if (active) {
    *reinterpret_cast<float4*>(&ua[(i + 1) * ULW + cb]) =
        make_float4(rr[0], rr[1], rr[2], rr[3]);
  }
  __syncthreads();
  float* src = ua;
  float* dst = ub;
  for (int q = 0; q < 9; ++q) {
    int lo = q + 1, hi = 35 - q;
    if (active && i >= lo && i < hi && (4 * j4 + 4) > lo && (4 * j4) < hi) {
      float eA[6], eB[6], eC[6];
      row_win(src + i * ULW + cb, eA);
      row_win(src + (i + 1) * ULW + cb, eB);
      row_win(src + (i + 2) * ULW + cb, eC);
      float res[4];
#pragma unroll
      for (int k = 0; k < 4; ++k) {
        float a = fmaxf(fmaxf(eA[k], eA[k + 1]), eA[k + 2]);
        float c = fmaxf(fmaxf(eC[k], eC[k + 1]), eC[k + 2]);
        float b = fmaxf(eB[k], eB[k + 2]);
        float m = fmaxf(fmaxf(a, c), b);
        res[k] = m * pp[k] + rr[k];
      }
      *reinterpret_cast<float4*>(&dst[(i + 1) * ULW + cb]) =
          make_float4(res[0], res[1], res[2], res[3]);
    }
    __syncthreads();
    float* t_ = src;
    src = dst;
    dst = t_;
  }
  if (active && i >= 10 && i < 26 && (4 * j4 + 4) > 10 && (4 * j4) < 26) {
    float eA[6], eB[6], eC[6];
    row_win(src + i * ULW + cb, eA);
    row_win(src + (i + 1) * ULW + cb, eB);
    row_win(src + (i + 2) * ULW + cb, eC);
#pragma unroll
    for (int k = 0; k < 4; ++k) {
      int cj = 4 * j4 + k;
      if (cj >= 10 && cj < 26) {
        float a = fmaxf(fmaxf(eA[k], eA[k + 1]), eA[k + 2]);
        float c = fmaxf(fmaxf(eC[k], eC[k + 1]), eC[k + 2]);
        float b = fmaxf(eB[k], eB[k + 2]);
        float m = fmaxf(fmaxf(a, c), b);
        vout[(ti * VTILE + i - 10) * HW + tj * VTILE + cj - 10] = m;
      }
    }
  }
}

// ---------------------------------------------------------------------------
// K5: all Wpol in one flat span_dot sweep (~12 µs in-situ). 2048 blocks.
// ---------------------------------------------------------------------------
__global__ __launch_bounds__(256) void mv_pol(const float4* __restrict__ Wpol,
                                              const float4* __restrict__ x,
                                              const float4* __restrict__ v,
                                              float* __restrict__ partP) {
  int b = blockIdx.x;
  int tid = threadIdx.x, wave = tid >> 6, lane = tid & 63;
  int f = b * 4 + wave;
  int row = f >> 8, rc = f & 255;
  const float4* __restrict__ wp = Wpol + (size_t)f * CH4 + lane;
  const float4* __restrict__ xp =
      (rc < 64) ? (v + (size_t)rc * CH4 + lane)
                : (x + (size_t)(rc - 64) * CH4 + lane);
  float acc = span_dot(wp, xp);
  acc = wred(acc);
  if (lane == 0) partP[rc * 32 + row] = acc;
}

// ---------------------------------------------------------------------------
// K6: finish_pol (1 block).
// ---------------------------------------------------------------------------
__global__ __launch_bounds__(1024) void finish_pol(
    const float* __restrict__ partP, const float* __restrict__ bpol,
    const float* __restrict__ Whead, const float* __restrict__ bhead,
    const float* __restrict__ v, const int* __restrict__ pos,
    float* __restrict__ out) {
  __shared__ float red[32][32];
  __shared__ float hp[32];
  __shared__ float logits[8];
  int tid = threadIdx.x;
  int row = tid & 31, grp = tid >> 5;
  float s = 0.f;
  for (int b = grp; b < 256; b += 32) s += partP[b * 32 + row];
  red[grp][row] = s;
  __syncthreads();
  if (tid < 32) {
    float t = bpol[tid];
    for (int g = 0; g < 32; ++g) t += red[g][tid];
    hp[tid] = fmaxf(t, 0.f);
  }
  __syncthreads();
  if (tid < 8) {
    float t = bhead[tid];
    for (int k = 0; k < 32; ++k) t += Whead[tid * 32 + k] * hp[k];
    logits[tid] = t;
  }
  __syncthreads();
  if (tid == 0) {
    float mx = logits[0];
    for (int j = 1; j < 8; ++j) mx = fmaxf(mx, logits[j]);
    float e[8], sum = 0.f;
    for (int j = 0; j < 8; ++j) {
      e[j] = __expf(logits[j] - mx);
      sum += e[j];
    }
    for (int j = 0; j < 8; ++j) out[j] = e[j] / sum;
    out[8] = v[pos[0] * HW + pos[1]];
  }
}

extern "C" void kernel_launch(void* const* d_in, const int* in_sizes, int n_in,
                              void* d_out, int out_size, void* d_ws,
                              size_t ws_size, hipStream_t stream) {
  const float* x = (const float*)d_in[0];
  const int* pos = (const int*)d_in[1];
  const float* W1 = (const float*)d_in[2];
  const float* b1 = (const float*)d_in[3];
  const float* W2 = (const float*)d_in[4];
  const float* b2 = (const float*)d_in[5];
  const float* Wro = (const float*)d_in[6];
  const float* bro = (const float*)d_in[7];
  const float* Wri = (const float*)d_in[8];
  const float* bri = (const float*)d_in[9];
  const float* Wp = (const float*)d_in[10];
  const float* bp = (const float*)d_in[11];
  const float* Wpol = (const float*)d_in[12];
  const float* bpol = (const float*)d_in[13];
  const float* Whead = (const float*)d_in[14];
  const float* bhead = (const float*)d_in[15];
  float* ws = (float*)d_ws;
  float* out = (float*)d_out;

  float* part1 = ws + WS_PART1;
  float* partP = ws + WS_PARTP;
  float* h2 = ws + WS_H2;
  float* drob = ws + WS_DRO;
  float* drib = ws + WS_DRI;
  float* dpb = ws + WS_DP;
  float* vbuf = ws + WS_V;

  // K1: W1@x partials
  mv_w1<<<1536, 256, 0, stream>>>((const float4*)W1, (const float4*)x, part1);
  // K2: h1 -> h2
  finish_h<<<1, 1024, 0, stream>>>(part1, b1, W2, b2, h2);
  // K3: raw dots for Wro/Wri/Wp (homogeneous mv_pol-shaped blocks)
  rop_part<<<3072, 256, 0, stream>>>((const float4*)Wro, (const float4*)Wri,
                                     (const float4*)Wp, h2, drob, drib, dpb);
  // K4: sigmoid/combine + 10 value-iteration steps
  valiter_kernel<<<1024, 384, 0, stream>>>(drob, drib, dpb, bro, bri, bp,
                                           vbuf);
  // K5: all Wpol partials
  mv_pol<<<2048, 256, 0, stream>>>((const float4*)Wpol, (const float4*)x,
                                   (const float4*)vbuf, partP);
  // K6: heads + softmax + state value
  finish_pol<<<1, 1024, 0, stream>>>(partP, bpol, Whead, bhead, vbuf, pos,
                                     out);
}

// Round 22
// 104.217 us; speedup vs baseline: 1.2670x; 1.1061x over previous
//
#include <hip/hip_runtime.h>

#define HW 512
#define NSTATE (HW * HW)   // 262144
#define NC4_X 196608       // x as float4 (3*H*W/4)
#define NC4_POLROW 262144  // Wpol row stride in float4 (4 MiB)
#define NC4_V 65536        // v as float4

#define CH4 1024   // float4 per wave-chunk (16 KB)
#define NCH_X 192  // chunks per W1 row

// ws layout (float offsets)
#define WS_PART1 0       // 6144
#define WS_PARTP 6144    // 8192
#define WS_H2 14336      // 64
#define WS_DRO 16384     // 262144
#define WS_DRI 278528    // 262144
#define WS_DP 540672     // 262144
#define WS_V 802816      // 262144

#define SGB __builtin_amdgcn_sched_group_barrier

typedef float f4v __attribute__((ext_vector_type(4)));

__device__ __forceinline__ float wred(float a) {
  a += __shfl_xor(a, 32);
  a += __shfl_xor(a, 16);
  a += __shfl_xor(a, 8);
  a += __shfl_xor(a, 4);
  a += __shfl_xor(a, 2);
  a += __shfl_xor(a, 1);
  return a;
}

__device__ __forceinline__ float span_dot(const float4* __restrict__ wp,
                                          const float4* __restrict__ xp) {
  float acc = 0.f;
#pragma unroll
  for (int bt = 0; bt < 2; ++bt) {
    float4 w[8], xv[8];
#pragma unroll
    for (int j = 0; j < 8; ++j) w[j] = wp[bt * 512 + j * 64];
#pragma unroll
    for (int j = 0; j < 8; ++j) xv[j] = xp[bt * 512 + j * 64];
    SGB(0x020, 16, 0);
#pragma unroll
    for (int j = 0; j < 8; ++j)
      acc += w[j].x * xv[j].x + w[j].y * xv[j].y + w[j].z * xv[j].z +
             w[j].w * xv[j].w;
  }
  return acc;
}

// ---------------------------------------------------------------------------
// K1: W1@x partials, flat-linear span_dot. 1536 blocks. W1 (100 MB) stays
// L3-resident once rop's matrices are marked non-temporal.
// ---------------------------------------------------------------------------
__global__ __launch_bounds__(256) void mv_w1(const float4* __restrict__ W1,
                                             const float4* __restrict__ x,
                                             float* __restrict__ part1) {
  int b = blockIdx.x;
  int row = b / 48, cb = b - row * 48;
  int tid = threadIdx.x, wave = tid >> 6, lane = tid & 63;
  int ch = cb * 4 + wave;
  const float4* __restrict__ wp =
      W1 + (size_t)row * NC4_X + (size_t)ch * CH4 + lane;
  const float4* __restrict__ xp = x + (size_t)ch * CH4 + lane;
  float acc = span_dot(wp, xp);
  acc = wred(acc);
  if (lane == 0) part1[ch * 32 + row] = acc;
}

// ---------------------------------------------------------------------------
// K2: finish_h (1 block).
// ---------------------------------------------------------------------------
__global__ __launch_bounds__(1024) void finish_h(
    const float* __restrict__ partials, const float* __restrict__ b1,
    const float* __restrict__ W2, const float* __restrict__ b2,
    float* __restrict__ h2out) {
  __shared__ float red[32][32];
  __shared__ float h1[32];
  int tid = threadIdx.x;
  int row = tid & 31, grp = tid >> 5;
  float s = 0.f;
  for (int b = grp; b < NCH_X; b += 32) s += partials[b * 32 + row];
  red[grp][row] = s;
  __syncthreads();
  if (tid < 32) {
    float t = b1[tid];
    for (int g = 0; g < 32; ++g) t += red[g][tid];
    h1[tid] = fmaxf(t, 0.f);
  }
  __syncthreads();
  if (tid < 64) {
    float t = b2[tid];
    for (int k = 0; k < 32; ++k) t += W2[tid * 32 + k] * h1[k];
    h2out[tid] = fmaxf(t, 0.f);
  }
}

// ---------------------------------------------------------------------------
// K3: rop_part with NON-TEMPORAL W loads (R22). 21-round diagnosis: the
// Wro/Wri/Wp bytes cycle through a 423 MB working set > 256 MB L3; they end
// up ~50% L3-resident, and the line-granular hit/miss INTERLEAVE destroys
// HBM stream efficiency (R19: FETCH=100 MB of 192, 1.3 TB/s). nt loads
// (a) make this stream pure-HBM (no interleave), (b) stop it evicting
// x+W1+Wpol (231 MB — now stably L3-resident). Code otherwise = R21.
// ---------------------------------------------------------------------------
__global__ __launch_bounds__(256) void rop_part(
    const float4* __restrict__ Wro4, const float4* __restrict__ Wri4,
    const float4* __restrict__ Wp4, const float* __restrict__ h2,
    float* __restrict__ dro, float* __restrict__ dri,
    float* __restrict__ dp) {
  __shared__ float dots[4][64];
  int b = blockIdx.x;  // [0,3072)
  int m = b >> 10;     // matrix 0..2
  int c = b & 1023;    // 64KB chunk
  int tid = threadIdx.x, wave = tid >> 6, lane = tid & 63;
  int k = lane & 15, grp = lane >> 4;
  const float4* __restrict__ W = (m == 0) ? Wro4 : ((m == 1) ? Wri4 : Wp4);
  float* __restrict__ D = (m == 0) ? dro : ((m == 1) ? dri : dp);
  float4 h4 = ((const float4*)h2)[k];
  const f4v* __restrict__ wp =
      (const f4v*)(W + ((size_t)c * 4 + wave) * 1024 + lane);
  float part[16];
#pragma unroll
  for (int bt = 0; bt < 2; ++bt) {
    f4v w[8];
#pragma unroll
    for (int j = 0; j < 8; ++j)
      w[j] = __builtin_nontemporal_load(wp + (bt * 8 + j) * 64);
    SGB(0x020, 8, 0);
#pragma unroll
    for (int j = 0; j < 8; ++j)
      part[bt * 8 + j] =
          w[j][0] * h4.x + w[j][1] * h4.y + w[j][2] * h4.z + w[j][3] * h4.w;
  }
#pragma unroll
  for (int j = 0; j < 16; ++j) {
    part[j] += __shfl_xor(part[j], 8);
    part[j] += __shfl_xor(part[j], 4);
    part[j] += __shfl_xor(part[j], 2);
    part[j] += __shfl_xor(part[j], 1);
  }
  if (k == 0) {
#pragma unroll
    for (int j = 0; j < 16; ++j) dots[wave][j * 4 + grp] = part[j];
  }
  __syncthreads();
  D[(size_t)c * 256 + tid] = dots[tid >> 6][tid & 63];
}

// ---------------------------------------------------------------------------
// K4: valiter (R17 structure) + sigmoid/bias/combine in the load stage.
// ---------------------------------------------------------------------------
#define VTILE 16
#define VHALO 10
#define ULW 44
#define ULH 38
__device__ __forceinline__ void row_win(const float* __restrict__ r,
                                        float e[6]) {
  float4 L = *reinterpret_cast<const float4*>(r - 4);
  float4 M = *reinterpret_cast<const float4*>(r);
  float4 R = *reinterpret_cast<const float4*>(r + 4);
  e[0] = L.w; e[1] = M.x; e[2] = M.y; e[3] = M.z; e[4] = M.w; e[5] = R.x;
}
__global__ __launch_bounds__(384) void valiter_kernel(
    const float* __restrict__ dro, const float* __restrict__ dri,
    const float* __restrict__ dp, const float* __restrict__ bro,
    const float* __restrict__ bri, const float* __restrict__ bp,
    float* __restrict__ vout) {
  __shared__ float ua[ULH * ULW];
  __shared__ float ub[ULH * ULW];
  int tid = threadIdx.x;
  int blk = blockIdx.x;
  int ti = blk >> 5, tj = blk & 31;
  for (int idx = tid; idx < ULH * ULW; idx += 384) {
    ua[idx] = 0.f;
    ub[idx] = 0.f;
  }
  int i = tid / 9, j4 = tid - i * 9;
  bool active = (i < 36);
  int cb = 4 + 4 * j4;
  float pp[4], rr[4];
  if (active) {
    int gi = ti * VTILE - VHALO + i;
    int gj0 = tj * VTILE - VHALO + 4 * j4;
#pragma unroll
    for (int k = 0; k < 4; ++k) {
      int gj = gj0 + k;
      bool ok = (gi >= 0) & (gi < HW) & (gj >= 0) & (gj < HW);
      if (ok) {
        int g = gi * HW + gj;
        float sro = 1.f / (1.f + __expf(-(dro[g] + bro[g])));
        float sri = 1.f / (1.f + __expf(-(dri[g] + bri[g])));
        pp[k] = 1.f / (1.f + __expf(-(dp[g] + bp[g])));
        rr[k] = sri - sro;
      } else {
        pp[k] = 0.f;
        rr[k] = 0.f;
      }
    }
  }
  __syncthreads();
  if (active) {
    *reinterpret_cast<float4*>(&ua[(i + 1) * ULW + cb]) =
        make_float4(rr[0], rr[1], rr[2], rr[3]);
  }
  __syncthreads();
  float* src = ua;
  float* dst = ub;
  for (int q = 0; q < 9; ++q) {
    int lo = q + 1, hi = 35 - q;
    if (active && i >= lo && i < hi && (4 * j4 + 4) > lo && (4 * j4) < hi) {
      float eA[6], eB[6], eC[6];
      row_win(src + i * ULW + cb, eA);
      row_win(src + (i + 1) * ULW + cb, eB);
      row_win(src + (i + 2) * ULW + cb, eC);
      float res[4];
#pragma unroll
      for (int k = 0; k < 4; ++k) {
        float a = fmaxf(fmaxf(eA[k], eA[k + 1]), eA[k + 2]);
        float c = fmaxf(fmaxf(eC[k], eC[k + 1]), eC[k + 2]);
        float b = fmaxf(eB[k], eB[k + 2]);
        float m = fmaxf(fmaxf(a, c), b);
        res[k] = m * pp[k] + rr[k];
      }
      *reinterpret_cast<float4*>(&dst[(i + 1) * ULW + cb]) =
          make_float4(res[0], res[1], res[2], res[3]);
    }
    __syncthreads();
    float* t_ = src;
    src = dst;
    dst = t_;
  }
  if (active && i >= 10 && i < 26 && (4 * j4 + 4) > 10 && (4 * j4) < 26) {
    float eA[6], eB[6], eC[6];
    row_win(src + i * ULW + cb, eA);
    row_win(src + (i + 1) * ULW + cb, eB);
    row_win(src + (i + 2) * ULW + cb, eC);
#pragma unroll
    for (int k = 0; k < 4; ++k) {
      int cj = 4 * j4 + k;
      if (cj >= 10 && cj < 26) {
        float a = fmaxf(fmaxf(eA[k], eA[k + 1]), eA[k + 2]);
        float c = fmaxf(fmaxf(eC[k], eC[k + 1]), eC[k + 2]);
        float b = fmaxf(eB[k], eB[k + 2]);
        float m = fmaxf(fmaxf(a, c), b);
        vout[(ti * VTILE + i - 10) * HW + tj * VTILE + cj - 10] = m;
      }
    }
  }
}

// ---------------------------------------------------------------------------
// K5: all Wpol in one flat span_dot sweep. 2048 blocks. Wpol (128 MB) now
// L3-resident alongside W1 once rop's stream is non-temporal.
// ---------------------------------------------------------------------------
__global__ __launch_bounds__(256) void mv_pol(const float4* __restrict__ Wpol,
                                              const float4* __restrict__ x,
                                              const float4* __restrict__ v,
                                              float* __restrict__ partP) {
  int b = blockIdx.x;
  int tid = threadIdx.x, wave = tid >> 6, lane = tid & 63;
  int f = b * 4 + wave;
  int row = f >> 8, rc = f & 255;
  const float4* __restrict__ wp = Wpol + (size_t)f * CH4 + lane;
  const float4* __restrict__ xp =
      (rc < 64) ? (v + (size_t)rc * CH4 + lane)
                : (x + (size_t)(rc - 64) * CH4 + lane);
  float acc = span_dot(wp, xp);
  acc = wred(acc);
  if (lane == 0) partP[rc * 32 + row] = acc;
}

// ---------------------------------------------------------------------------
// K6: finish_pol (1 block).
// ---------------------------------------------------------------------------
__global__ __launch_bounds__(1024) void finish_pol(
    const float* __restrict__ partP, const float* __restrict__ bpol,
    const float* __restrict__ Whead, const float* __restrict__ bhead,
    const float* __restrict__ v, const int* __restrict__ pos,
    float* __restrict__ out) {
  __shared__ float red[32][32];
  __shared__ float hp[32];
  __shared__ float logits[8];
  int tid = threadIdx.x;
  int row = tid & 31, grp = tid >> 5;
  float s = 0.f;
  for (int b = grp; b < 256; b += 32) s += partP[b * 32 + row];
  red[grp][row] = s;
  __syncthreads();
  if (tid < 32) {
    float t = bpol[tid];
    for (int g = 0; g < 32; ++g) t += red[g][tid];
    hp[tid] = fmaxf(t, 0.f);
  }
  __syncthreads();
  if (tid < 8) {
    float t = bhead[tid];
    for (int k = 0; k < 32; ++k) t += Whead[tid * 32 + k] * hp[k];
    logits[tid] = t;
  }
  __syncthreads();
  if (tid == 0) {
    float mx = logits[0];
    for (int j = 1; j < 8; ++j) mx = fmaxf(mx, logits[j]);
    float e[8], sum = 0.f;
    for (int j = 0; j < 8; ++j) {
      e[j] = __expf(logits[j] - mx);
      sum += e[j];
    }
    for (int j = 0; j < 8; ++j) out[j] = e[j] / sum;
    out[8] = v[pos[0] * HW + pos[1]];
  }
}

extern "C" void kernel_launch(void* const* d_in, const int* in_sizes, int n_in,
                              void* d_out, int out_size, void* d_ws,
                              size_t ws_size, hipStream_t stream) {
  const float* x = (const float*)d_in[0];
  const int* pos = (const int*)d_in[1];
  const float* W1 = (const float*)d_in[2];
  const float* b1 = (const float*)d_in[3];
  const float* W2 = (const float*)d_in[4];
  const float* b2 = (const float*)d_in[5];
  const float* Wro = (const float*)d_in[6];
  const float* bro = (const float*)d_in[7];
  const float* Wri = (const float*)d_in[8];
  const float* bri = (const float*)d_in[9];
  const float* Wp = (const float*)d_in[10];
  const float* bp = (const float*)d_in[11];
  const float* Wpol = (const float*)d_in[12];
  const float* bpol = (const float*)d_in[13];
  const float* Whead = (const float*)d_in[14];
  const float* bhead = (const float*)d_in[15];
  float* ws = (float*)d_ws;
  float* out = (float*)d_out;

  float* part1 = ws + WS_PART1;
  float* partP = ws + WS_PARTP;
  float* h2 = ws + WS_H2;
  float* drob = ws + WS_DRO;
  float* drib = ws + WS_DRI;
  float* dpb = ws + WS_DP;
  float* vbuf = ws + WS_V;

  // K1: W1@x partials
  mv_w1<<<1536, 256, 0, stream>>>((const float4*)W1, (const float4*)x, part1);
  // K2: h1 -> h2
  finish_h<<<1, 1024, 0, stream>>>(part1, b1, W2, b2, h2);
  // K3: raw dots for Wro/Wri/Wp — NON-TEMPORAL stream
  rop_part<<<3072, 256, 0, stream>>>((const float4*)Wro, (const float4*)Wri,
                                     (const float4*)Wp, h2, drob, drib, dpb);
  // K4: sigmoid/combine + 10 value-iteration steps
  valiter_kernel<<<1024, 384, 0, stream>>>(drob, drib, dpb, bro, bri, bp,
                                           vbuf);
  // K5: all Wpol partials
  mv_pol<<<2048, 256, 0, stream>>>((const float4*)Wpol, (const float4*)x,
                                   (const float4*)vbuf, partP);
  // K6: heads + softmax + state value
  finish_pol<<<1, 1024, 0, stream>>>(partP, bpol, Whead, bhead, vbuf, pos,
                                     out);
}